// Round 18
// baseline (523.132 us; speedup 1.0000x reference)
//
#include <hip/hip_runtime.h>
#include <hip/hip_bf16.h>

typedef __attribute__((ext_vector_type(8))) short short8;
typedef __attribute__((ext_vector_type(4))) short short4v;
typedef __attribute__((ext_vector_type(4))) float f32x4;
using bf16 = __hip_bfloat16;
using lds_bf16 = __attribute__((address_space(3))) bf16;

#define BARF()  asm volatile("s_barrier" ::: "memory")
#define LGKM0() asm volatile("s_waitcnt lgkmcnt(0)" ::: "memory")
#define VMC4()  asm volatile("s_waitcnt vmcnt(4)" ::: "memory")
#define VMC2()  asm volatile("s_waitcnt vmcnt(2)" ::: "memory")
#define VMC0()  asm volatile("s_waitcnt vmcnt(0)" ::: "memory")
#define SCHED0() __builtin_amdgcn_sched_barrier(0)
#define PRIO1() __builtin_amdgcn_s_setprio(1)
#define PRIO0() __builtin_amdgcn_s_setprio(0)

static __device__ __forceinline__ short bfb(float f) {
  bf16 h = __float2bfloat16(f);
  short r; __builtin_memcpy(&r, &h, 2); return r;
}
static __device__ __forceinline__ float b2f(short s) {
  bf16 h; __builtin_memcpy(&h, &s, 2); return __bfloat162float(h);
}

static __device__ __forceinline__ void gld_lds16(const bf16* g, bf16* l) {
  __builtin_amdgcn_global_load_lds(
      (const __attribute__((address_space(1))) void*)g,
      (__attribute__((address_space(3))) void*)l, 16, 0, 0);
}

// opaque LDS read: no compiler-inserted vmcnt vs global_load_lds DMA
static __device__ __forceinline__ short8 dsr(const lds_bf16* b, int imm) {
  short8 v;
  asm volatile("ds_read_b128 %0, %1 offset:%2" : "=v"(v) : "v"(b), "i"(imm));
  return v;
}

// ------- fused prep: fp32->bf16 weight convert (blocks 0..8191) + t-projections (blocks 8192..8287) -------
__global__ __launch_bounds__(256) void prep_kernel(
    const float* __restrict__ s0, const float* __restrict__ s1, const float* __restrict__ s2,
    const float* __restrict__ s3, const float* __restrict__ gw, const float* __restrict__ hw,
    const float* __restrict__ ow, bf16* __restrict__ dbase,
    const float* __restrict__ t,
    const float* __restrict__ w0, const float* __restrict__ w1, const float* __restrict__ w2,
    const float* __restrict__ w3, const float* __restrict__ w4, const float* __restrict__ w5,
    float* __restrict__ tout) {
  if (blockIdx.x >= 8192) {           // tproj part: 96 blocks * 256 = 24576
    int gid = ((int)blockIdx.x - 8192) * 256 + threadIdx.x;
    int s = gid >> 12, rem = gid & 4095;
    int b = rem >> 10, n = rem & 1023;
    const float* w = (s == 0) ? w0 : (s == 1) ? w1 : (s == 2) ? w2 : (s == 3) ? w3 : (s == 4) ? w4 : w5;
    const float4* tv = (const float4*)(t + b * 256);
    const float4* wv = (const float4*)(w + n * 256);
    float acc = 0.f;
    #pragma unroll 8
    for (int j = 0; j < 64; ++j) {
      float4 a = tv[j], c = wv[j];
      acc += a.x * c.x + a.y * c.y + a.z * c.z + a.w * c.w;
    }
    tout[gid] = acc;
    return;
  }
  size_t c = (size_t)blockIdx.x * 256 + threadIdx.x;   // chunk of 8 elements
  const float* src; size_t se;
  if (c < 524288) {
    int seg = (int)(c >> 17);
    src = (seg == 0) ? s0 : (seg == 1) ? s1 : (seg == 2) ? s2 : s3;
    se = (c - ((size_t)seg << 17)) * 8;
  } else if (c < 1572864) {
    size_t lc = c - 524288;
    size_t row = lc >> 7;                  // 0..8191 interleaved rows
    src = (row & 1) ? hw : gw;
    se = ((row >> 1) << 10) + ((lc & 127) << 3);
  } else { src = ow; se = (c - 1572864) * 8; }
  float4 v0 = *(const float4*)(src + se);
  float4 v1 = *(const float4*)(src + se + 4);
  short8 o;
  o[0] = bfb(v0.x); o[1] = bfb(v0.y); o[2] = bfb(v0.z); o[3] = bfb(v0.w);
  o[4] = bfb(v1.x); o[5] = bfb(v1.y); o[6] = bfb(v1.z); o[7] = bfb(v1.w);
  *(short8*)(dbase + c * 8) = o;
}

// ---------------- AdaRMSNorm (fp32 or bf16 input) ----------------
template<int BF16IN>
__global__ __launch_bounds__(256) void ada_rms_kernel(const void* __restrict__ xin,
    const float* __restrict__ gamma, const float* __restrict__ beta, bf16* __restrict__ out) {
  int row = blockIdx.x;            // 8192 rows
  int b = row >> 11;
  int tid = threadIdx.x;
  float vx, vy, vz, vw;
  if constexpr (BF16IN) {
    const bf16* xr = (const bf16*)xin + (size_t)row * 1024;
    short4v v = *(const short4v*)(xr + tid * 4);
    vx = b2f(v[0]); vy = b2f(v[1]); vz = b2f(v[2]); vw = b2f(v[3]);
  } else {
    const float* xr = (const float*)xin + (size_t)row * 1024;
    float4 v = *(const float4*)(xr + tid * 4);
    vx = v.x; vy = v.y; vz = v.z; vw = v.w;
  }
  float ss = vx * vx + vy * vy + vz * vz + vw * vw;
  #pragma unroll
  for (int m = 1; m < 64; m <<= 1) ss += __shfl_xor(ss, m);
  __shared__ float red[4];
  if ((tid & 63) == 0) red[tid >> 6] = ss;
  __syncthreads();
  float tot = red[0] + red[1] + red[2] + red[3];
  float rinv = rsqrtf(tot * (1.0f / 1024.0f) + 1e-6f);
  const float* g  = gamma + b * 1024 + tid * 4;
  const float* be = beta  + b * 1024 + tid * 4;
  short4v o;
  o[0] = bfb(g[0] * vx * rinv + be[0]);
  o[1] = bfb(g[1] * vy * rinv + be[1]);
  o[2] = bfb(g[2] * vz * rinv + be[2]);
  o[3] = bfb(g[3] * vw * rinv + be[3]);
  *(short4v*)(out + (size_t)row * 1024 + tid * 4) = o;
}

// ================= 256xBN 8-phase GEMM: asm ds_read + counted vmcnt =================
// BN=256 for GH (K=1024: max MFMA per phase); BN=128 only for FIN (K=4096, NITER=32).
enum { EPI8_GH = 1, EPI8_FIN = 2 };

#define RDA_M(d, mh) { \
  _Pragma("unroll") for (int mq = 0; mq < 4; ++mq) { \
    a[mq][0] = dsr(aB0, (d) * 32768 + ((mh) * 4 + mq) * 2048); \
    a[mq][1] = dsr(aB1, (d) * 32768 + ((mh) * 4 + mq) * 2048); } }
#define RDB0_M(d, nh) { \
  _Pragma("unroll") for (int nq = 0; nq < 2; ++nq) { \
    b0[nq][0] = dsr(bB0, (d) * 32768 + ((nh) * 2 + nq) * 2048); \
    b0[nq][1] = dsr(bB1, (d) * 32768 + ((nh) * 2 + nq) * 2048); } }
#define RDB1_M(d, nh) { \
  _Pragma("unroll") for (int nq = 0; nq < 2; ++nq) { \
    b1[nq][0] = dsr(bB0, (d) * 32768 + ((nh) * 2 + nq) * 2048); \
    b1[nq][1] = dsr(bB1, (d) * 32768 + ((nh) * 2 + nq) * 2048); } }
#define RDB0_F(d) { b0[0][0] = dsr(bB0, (d) * 16384); b0[0][1] = dsr(bB1, (d) * 16384); }
#define RDB1_F(d) { b1[0][0] = dsr(bB0, (d) * 16384 + 2048); b1[0][1] = dsr(bB1, (d) * 16384 + 2048); }

template<int EPI, int BN>
__global__ __launch_bounds__(512, 2) void gemm8p_kernel(
    const bf16* __restrict__ A, const bf16* __restrict__ B,
    int N, int K,
    bf16* __restrict__ o1, float* __restrict__ outF,
    const float* __restrict__ aux1, const float* __restrict__ aux2,
    const float* __restrict__ bias)
{
  constexpr int SB_ELEMS = (BN == 256) ? (2 * 2 * 128 * 64) : (2 * 128 * 64);
  __shared__ __align__(16) bf16 sA[2 * 2 * 128 * 64];  // [dbuf][half][128][64]
  __shared__ __align__(16) bf16 sB[SB_ELEMS];
  const int tid = threadIdx.x;
  const int lane = tid & 63, w = tid >> 6;             // 8 waves: 2M x 4N
  const int wr = w >> 2, wcn = w & 3;
  const int bid = (int)blockIdx.x;
  const int ntn = (BN == 256) ? (N >> 8) : (N >> 7);
  const int trow = (bid / ntn) << 8;
  const int tcol = (bid % ntn) * BN;
  const int fr = lane & 15, hi = lane >> 4;
  const int rbase = hi << 2;
  const int NITER = K >> 7;                            // 2 K-tiles (BK=64) per iter
  const int st_row = (w << 4) + (lane >> 3);           // 0..127 within a half
  const int st_col = (((lane & 7) ^ ((lane >> 3) & 7)) << 3);
  const bf16* AsH0 = A + (size_t)(trow + st_row) * K + st_col;
  const bf16* AsH1 = AsH0 + (size_t)128 * K;
  const bf16* BsH0 = B + (size_t)(tcol + st_row) * K + st_col;
  const bf16* BsH1 = BsH0 + (size_t)128 * K;           // only for BN==256
  const size_t K8 = (size_t)K << 3;
  bf16* dA = sA + (w << 10);
  bf16* dB = sB + (w << 10);

  auto stA = [&](int dbuf, int h, int t) {
    const bf16* s = (h ? AsH1 : AsH0) + (t << 6);
    bf16* d = dA + ((dbuf * 2 + h) << 13);
    gld_lds16(s, d);
    gld_lds16(s + K8, d + 512);
  };
  auto stB2 = [&](int dbuf, int h, int t) {            // BN=256
    const bf16* s = (h ? BsH1 : BsH0) + (t << 6);
    bf16* d = dB + ((dbuf * 2 + h) << 13);
    gld_lds16(s, d);
    gld_lds16(s + K8, d + 512);
  };
  auto stB1 = [&](int dbuf, int t) {                   // BN=128
    const bf16* s = BsH0 + (t << 6);
    bf16* d = dB + (dbuf << 13);
    gld_lds16(s, d);
    gld_lds16(s + K8, d + 512);
  };
  const int colK0 = (hi << 3) ^ ((fr & 7) << 3);
  const int colK1 = (32 + (hi << 3)) ^ ((fr & 7) << 3);
  const lds_bf16* aB0 = (const lds_bf16*)(sA + (wr << 13) + (fr << 6) + colK0);
  const lds_bf16* aB1 = (const lds_bf16*)(sA + (wr << 13) + (fr << 6) + colK1);
  const lds_bf16 *bB0, *bB1;
  if constexpr (BN == 256) {
    bB0 = (const lds_bf16*)(sB + ((wcn >> 1) << 13) + ((wcn & 1) << 12) + (fr << 6) + colK0);
    bB1 = (const lds_bf16*)(sB + ((wcn >> 1) << 13) + ((wcn & 1) << 12) + (fr << 6) + colK1);
  } else {
    bB0 = (const lds_bf16*)(sB + (wcn << 11) + (fr << 6) + colK0);
    bB1 = (const lds_bf16*)(sB + (wcn << 11) + (fr << 6) + colK1);
  }

  f32x4 acc[8][BN / 64] = {};
  short8 a[4][2], b0[2][2], b1[2][2];

  if constexpr (BN == 256) {
    auto QUAD0 = [&](int mh, int nh) {
      #pragma unroll
      for (int kk = 0; kk < 2; ++kk)
        #pragma unroll
        for (int mq = 0; mq < 4; ++mq)
          #pragma unroll
          for (int nq = 0; nq < 2; ++nq)
            acc[mh * 4 + mq][nh * 2 + nq] = __builtin_amdgcn_mfma_f32_16x16x32_bf16(
                a[mq][kk], b0[nq][kk], acc[mh * 4 + mq][nh * 2 + nq], 0, 0, 0);
    };
    auto QUAD1 = [&](int mh, int nh) {
      #pragma unroll
      for (int kk = 0; kk < 2; ++kk)
        #pragma unroll
        for (int mq = 0; mq < 4; ++mq)
          #pragma unroll
          for (int nq = 0; nq < 2; ++nq)
            acc[mh * 4 + mq][nh * 2 + nq] = __builtin_amdgcn_mfma_f32_16x16x32_bf16(
                a[mq][kk], b1[nq][kk], acc[mh * 4 + mq][nh * 2 + nq], 0, 0, 0);
    };
    stB2(0, 0, 0); stB2(0, 1, 0); stA(0, 0, 0); stA(0, 1, 0);
    stB2(1, 0, 1); stB2(1, 1, 1);
    VMC4();
    BARF();
    for (int i = 0; i < NITER; ++i) {
      const int t1 = 2 * i + 1, tn0 = 2 * i + 2, tn1 = 2 * i + 3;
      const bool g = (i != NITER - 1);
      RDA_M(0, 0); RDB0_M(0, 0);
      stA(1, 0, t1);
      BARF(); LGKM0(); SCHED0(); PRIO1(); QUAD0(0, 0); PRIO0(); BARF();
      RDB1_M(0, 1);
      stA(1, 1, t1);
      BARF(); LGKM0(); SCHED0(); PRIO1(); QUAD1(0, 1); PRIO0(); BARF();
      RDA_M(0, 1);
      if (g) stB2(0, 0, tn0);
      BARF(); LGKM0(); SCHED0(); PRIO1(); QUAD1(1, 1); PRIO0(); BARF();
      if (g) stB2(0, 1, tn0);
      BARF(); LGKM0(); SCHED0(); PRIO1(); QUAD0(1, 0); PRIO0();
      if (g) { VMC4(); } else { VMC0(); }
      BARF();
      RDA_M(1, 0); RDB0_M(1, 0);
      if (g) stA(0, 0, tn0);
      BARF(); LGKM0(); SCHED0(); PRIO1(); QUAD0(0, 0); PRIO0(); BARF();
      RDB1_M(1, 1);
      if (g) stA(0, 1, tn0);
      BARF(); LGKM0(); SCHED0(); PRIO1(); QUAD1(0, 1); PRIO0(); BARF();
      RDA_M(1, 1);
      if (g) stB2(1, 0, tn1);
      BARF(); LGKM0(); SCHED0(); PRIO1(); QUAD1(1, 1); PRIO0(); BARF();
      if (g) stB2(1, 1, tn1);
      BARF(); LGKM0(); SCHED0(); PRIO1(); QUAD0(1, 0); PRIO0();
      if (g) { VMC4(); }
      BARF();
    }
  } else {
    auto QUADF0 = [&](int mh) {
      #pragma unroll
      for (int kk = 0; kk < 2; ++kk)
        #pragma unroll
        for (int mq = 0; mq < 4; ++mq)
          acc[mh * 4 + mq][0] = __builtin_amdgcn_mfma_f32_16x16x32_bf16(
              a[mq][kk], b0[0][kk], acc[mh * 4 + mq][0], 0, 0, 0);
    };
    auto QUADF1 = [&](int mh) {
      #pragma unroll
      for (int kk = 0; kk < 2; ++kk)
        #pragma unroll
        for (int mq = 0; mq < 4; ++mq)
          acc[mh * 4 + mq][1] = __builtin_amdgcn_mfma_f32_16x16x32_bf16(
              a[mq][kk], b1[0][kk], acc[mh * 4 + mq][1], 0, 0, 0);
    };
    stB1(0, 0); stA(0, 0, 0); stA(0, 1, 0); stB1(1, 1);
    VMC2();
    BARF();
    for (int i = 0; i < NITER; ++i) {
      const int t1 = 2 * i + 1, tn0 = 2 * i + 2, tn1 = 2 * i + 3;
      const bool g = (i != NITER - 1);
      RDA_M(0, 0); RDB0_F(0);
      stA(1, 0, t1);
      BARF(); LGKM0(); SCHED0(); PRIO1(); QUADF0(0); PRIO0(); BARF();
      RDB1_F(0);
      stA(1, 1, t1);
      BARF(); LGKM0(); SCHED0(); PRIO1(); QUADF1(0); PRIO0(); BARF();
      RDA_M(0, 1);
      if (g) stB1(0, tn0);
      BARF(); LGKM0(); SCHED0(); PRIO1(); QUADF1(1); PRIO0(); BARF();
      BARF(); LGKM0(); SCHED0(); PRIO1(); QUADF0(1); PRIO0();
      if (g) { VMC2(); } else { VMC0(); }
      BARF();
      RDA_M(1, 0); RDB0_F(1);
      if (g) stA(0, 0, tn0);
      BARF(); LGKM0(); SCHED0(); PRIO1(); QUADF0(0); PRIO0(); BARF();
      RDB1_F(1);
      if (g) stA(0, 1, tn0);
      BARF(); LGKM0(); SCHED0(); PRIO1(); QUADF1(0); PRIO0(); BARF();
      RDA_M(1, 1);
      if (g) stB1(1, tn1);
      BARF(); LGKM0(); SCHED0(); PRIO1(); QUADF1(1); PRIO0(); BARF();
      BARF(); LGKM0(); SCHED0(); PRIO1(); QUADF0(1); PRIO0();
      if (g) { VMC2(); }
      BARF();
    }
  }

  // epilogue
  #pragma unroll
  for (int m = 0; m < 8; ++m)
  #pragma unroll
  for (int n = 0; n < BN / 64; ++n)
  #pragma unroll
  for (int r = 0; r < 4; ++r) {
    int row = trow + (wr << 7) + m * 16 + rbase + r;
    int col = tcol + wcn * (BN / 4) + n * 16 + fr;
    float c = acc[m][n][r];
    if constexpr (EPI == EPI8_GH) {
      float other = __shfl_xor(c, 1);
      if (!(fr & 1)) {
        float sg = c / (1.f + __expf(-c));
        o1[(size_t)row * 4096 + (col >> 1)] = __float2bfloat16(sg * other);
      }
    } else {  // EPI8_FIN: out = xmid_b(bf16) + aux2*(c + bias)
      int b = row >> 11;
      size_t idx = (size_t)row * 1024 + col;
      outF[idx] = __bfloat162float(o1[idx]) + aux2[b * 1024 + col] * (c + bias[col]);
    }
  }
}

// ---------------- m97-structure GEMM: O-proj (bf16 xmid out), fused QKV ----------------
enum { EPI_RESID = 0, EPI_QKV3 = 2 };

template<int EPI>
__global__ __launch_bounds__(256) void gemm_bt_kernel(
    const bf16* __restrict__ A, const bf16* __restrict__ B,
    int N, int K,
    const float* __restrict__ aux1, const float* __restrict__ aux2,
    bf16* __restrict__ oq, bf16* __restrict__ okk, bf16* __restrict__ ovt)
{
  __shared__ __align__(16) bf16 As[128][32];
  __shared__ __align__(16) bf16 Bs[128][32];
  const int tid = threadIdx.x;
  const int lane = tid & 63, wid = tid >> 6;
  const int wr = wid >> 1, wc = wid & 1;
  const int bid = (int)blockIdx.x;
  const int ntn = N >> 7;
  const int trow = (bid / ntn) << 7;
  const int tcol = (bid % ntn) << 7;
  const int fr = lane & 15, fc = (lane >> 4) << 3;
  const int rbase = (lane >> 4) << 2;
  const bf16* gA0 = A + (size_t)(trow + wid * 32 + (lane >> 2)) * K + ((lane & 3) << 3);
  const bf16* gA1 = gA0 + (size_t)16 * K;
  const bf16* gB0 = B + (size_t)(tcol + wid * 32 + (lane >> 2)) * K + ((lane & 3) << 3);
  const bf16* gB1 = gB0 + (size_t)16 * K;
  bf16* lA0 = &As[wid * 32][0];
  bf16* lA1 = &As[wid * 32 + 16][0];
  bf16* lB0 = &Bs[wid * 32][0];
  bf16* lB1 = &Bs[wid * 32 + 16][0];
  f32x4 acc[4][4] = {};
  for (int k0 = 0; k0 < K; k0 += 32) {
    __syncthreads();
    gld_lds16(gA0 + k0, lA0);
    gld_lds16(gA1 + k0, lA1);
    gld_lds16(gB0 + k0, lB0);
    gld_lds16(gB1 + k0, lB1);
    __syncthreads();
    short8 af[4], bfr[4];
    #pragma unroll
    for (int m = 0; m < 4; ++m) af[m] = *(const short8*)&As[wr * 64 + m * 16 + fr][fc];
    #pragma unroll
    for (int n = 0; n < 4; ++n) bfr[n] = *(const short8*)&Bs[wc * 64 + n * 16 + fr][fc];
    #pragma unroll
    for (int m = 0; m < 4; ++m)
      #pragma unroll
      for (int n = 0; n < 4; ++n)
        acc[m][n] = __builtin_amdgcn_mfma_f32_16x16x32_bf16(af[m], bfr[n], acc[m][n], 0, 0, 0);
  }
  if constexpr (EPI == EPI_QKV3) {
    #pragma unroll
    for (int m = 0; m < 4; ++m)
    #pragma unroll
    for (int n = 0; n < 4; ++n) {
      int row0 = trow + wr * 64 + m * 16 + rbase;
      int col  = tcol + wc * 64 + n * 16 + fr;
      int seg = col >> 10, cc = col & 1023;
      int bb = row0 >> 11, h2 = cc >> 6, dd = cc & 63;
      if (seg == 0) {
        #pragma unroll
        for (int r = 0; r < 4; ++r) {
          int l = (row0 + r) & 2047;
          oq[(((size_t)(bb * 16 + h2) * 2048 + l) << 6) + dd] =
              __float2bfloat16(acc[m][n][r] * 0.18033688f);
        }
      } else if (seg == 1) {
        #pragma unroll
        for (int r = 0; r < 4; ++r) {
          int l = (row0 + r) & 2047;
          okk[(((size_t)(bb * 16 + h2) * 2048 + l) << 6) + dd] = __float2bfloat16(acc[m][n][r]);
        }
      } else {   // V^T: one b64 store
        int l = row0 & 2047;
        short4v o4;
        #pragma unroll
        for (int r = 0; r < 4; ++r) o4[r] = bfb(acc[m][n][r]);
        *(short4v*)&ovt[(((size_t)(bb * 16 + h2) * 64 + dd) << 11) + l] = o4;
      }
    }
  } else {  // EPI_RESID: xmid_b = bf16(x + alpha*c)
    #pragma unroll
    for (int m = 0; m < 4; ++m)
    #pragma unroll
    for (int n = 0; n < 4; ++n)
    #pragma unroll
    for (int r = 0; r < 4; ++r) {
      int row = trow + wr * 64 + m * 16 + rbase + r;
      int col = tcol + wc * 64 + n * 16 + fr;
      int b = row >> 11;
      size_t idx = (size_t)row * 1024 + col;
      oq[idx] = __float2bfloat16(aux1[idx] + aux2[b * 1024 + col] * acc[m][n][r]);
    }
  }
}

// ---------------- flash attention QBLK=256, 8 waves; dbuf LDS K/V, QK first ----------------
__global__ __launch_bounds__(512, 4) void attn_kernel(const bf16* __restrict__ q,
    const bf16* __restrict__ k, const bf16* __restrict__ vt, bf16* __restrict__ o) {
  const int id = blockIdx.x;
  const int bh = id & 63;
  const int qt = id >> 6;          // 0..7, 256 q-rows each
  const int b = bh >> 4, h = bh & 15;
  __shared__ __align__(16) bf16 Ks[2][64][72];   // [dbuf][kk][d]
  __shared__ __align__(16) bf16 Vs[2][64][72];   // [dbuf][d][kk]
  __shared__ __align__(16) bf16 Ps[256][72];     // [q_local][kk] (same-wave rows only)
  const int tid = threadIdx.x, lane = tid & 63, w = tid >> 6;   // 8 waves, 32 q-rows each
  const int fr = lane & 15, hi = lane >> 4;
  const int fc = hi << 3, rbase = hi << 2;
  const bf16* qbase = q + ((size_t)bh * 2048 + qt * 256) * 64;
  const bf16* kbase = k + (size_t)bh * 2048 * 64;
  const bf16* vbase = vt + (size_t)bh * 64 * 2048;
  short8 qf[2][2];
  #pragma unroll
  for (int nq = 0; nq < 2; ++nq)
    #pragma unroll
    for (int ks = 0; ks < 2; ++ks)
      qf[nq][ks] = *(const short8*)(qbase + (size_t)(w * 32 + nq * 16 + fr) * 64 + ks * 32 + fc);
  short8 onesf;
  #pragma unroll
  for (int j = 0; j < 8; ++j) onesf[j] = (short)0x3F80;   // bf16 1.0
  f32x4 accO[4][2] = {};
  f32x4 accD[2] = {};
  const int sr = tid >> 3, sc = (tid & 7) << 3;   // 512 threads: rows 0..63 x 8 col-chunks
  *(short8*)&Ks[0][sr][sc] = *(const short8*)(kbase + (size_t)sr * 64 + sc);
  *(short8*)&Vs[0][sr][sc] = *(const short8*)(vbase + (size_t)sr * 2048 + sc);
  short8 rk = *(const short8*)(kbase + (size_t)(64 + sr) * 64 + sc);
  short8 rv = *(const short8*)(vbase + (size_t)sr * 2048 + 64 + sc);
  __syncthreads();
  for (int kt = 0; kt < 2048; kt += 64) {
    const int cur = (kt >> 6) & 1;
    // QK^T first (reads current buffers immediately at tile top)
    f32x4 s[4][2] = {};
    #pragma unroll
    for (int ks = 0; ks < 2; ++ks) {
      short8 kf[4];
      #pragma unroll
      for (int mk = 0; mk < 4; ++mk) kf[mk] = *(const short8*)&Ks[cur][mk * 16 + fr][ks * 32 + fc];
      #pragma unroll
      for (int mk = 0; mk < 4; ++mk)
        #pragma unroll
        for (int nq = 0; nq < 2; ++nq)
          s[mk][nq] = __builtin_amdgcn_mfma_f32_16x16x32_bf16(kf[mk], qf[nq][ks], s[mk][nq], 0, 0, 0);
    }
    // stage tile t+1 into inactive buffer; issue t+2 loads (overlap with exp/P phase)
    if (kt + 64 < 2048) {
      *(short8*)&Ks[cur ^ 1][sr][sc] = rk;
      *(short8*)&Vs[cur ^ 1][sr][sc] = rv;
      if (kt + 128 < 2048) {
        rk = *(const short8*)(kbase + (size_t)(kt + 128 + sr) * 64 + sc);
        rv = *(const short8*)(vbase + (size_t)sr * 2048 + kt + 128 + sc);
      }
    }
    #pragma unroll
    for (int mk = 0; mk < 4; ++mk)
      #pragma unroll
      for (int nq = 0; nq < 2; ++nq) {
        short4v pk;
        pk[0] = bfb(exp2f(s[mk][nq][0]));
        pk[1] = bfb(exp2f(s[mk][nq][1]));
        pk[2] = bfb(exp2f(s[mk][nq][2]));
        pk[3] = bfb(exp2f(s[mk][nq][3]));
        *(short4v*)&Ps[w * 32 + nq * 16 + fr][mk * 16 + rbase] = pk;
      }
    #pragma unroll
    for (int ks2 = 0; ks2 < 2; ++ks2) {
      short8 av[4], bp[2];
      #pragma unroll
      for (int nd = 0; nd < 4; ++nd) av[nd] = *(const short8*)&Vs[cur][nd * 16 + fr][ks2 * 32 + fc];
      #pragma unroll
      for (int nq = 0; nq < 2; ++nq) bp[nq] = *(const short8*)&Ps[w * 32 + nq * 16 + fr][ks2 * 32 + fc];
      #pragma unroll
      for (int nd = 0; nd < 4; ++nd)
        #pragma unroll
        for (int nq = 0; nq < 2; ++nq)
          accO[nd][nq] = __builtin_amdgcn_mfma_f32_16x16x32_bf16(av[nd], bp[nq], accO[nd][nq], 0, 0, 0);
      #pragma unroll
      for (int nq = 0; nq < 2; ++nq)
        accD[nq] = __builtin_amdgcn_mfma_f32_16x16x32_bf16(onesf, bp[nq], accD[nq], 0, 0, 0);
    }
    __syncthreads();   // single barrier per tile
  }
  float rd[2];
  #pragma unroll
  for (int nq = 0; nq < 2; ++nq) rd[nq] = 1.0f / accD[nq][0];
  #pragma unroll
  for (int nd = 0; nd < 4; ++nd)
    #pragma unroll
    for (int nq = 0; nq < 2; ++nq) {
      short4v ov;
      #pragma unroll
      for (int r = 0; r < 4; ++r) ov[r] = bfb(accO[nd][nq][r] * rd[nq]);
      int qrow = qt * 256 + w * 32 + nq * 16 + fr;
      int col = h * 64 + nd * 16 + rbase;
      *(short4v*)&o[((size_t)b * 2048 + qrow) * 1024 + col] = ov;
    }
}

extern "C" void kernel_launch(void* const* d_in, const int* in_sizes, int n_in,
                              void* d_out, int out_size, void* d_ws, size_t ws_size,
                              hipStream_t stream) {
  (void)in_sizes; (void)n_in; (void)out_size; (void)ws_size;
  const float* x   = (const float*)d_in[0];
  const float* t   = (const float*)d_in[1];
  const float* agw = (const float*)d_in[2];
  const float* abw = (const float*)d_in[3];
  const float* wq  = (const float*)d_in[4];
  const float* wk  = (const float*)d_in[5];
  const float* wv  = (const float*)d_in[6];
  const float* wo  = (const float*)d_in[7];
  const float* aaw = (const float*)d_in[8];
  const float* fgw = (const float*)d_in[9];
  const float* fbw = (const float*)d_in[10];
  const float* gw  = (const float*)d_in[11];
  const float* hw  = (const float*)d_in[12];
  const float* ow  = (const float*)d_in[13];
  const float* ob  = (const float*)d_in[14];
  const float* faw = (const float*)d_in[15];
  float* out = (float*)d_out;

  char* p = (char*)d_ws;
  auto alloc = [&](size_t bytes) -> char* {
    char* r = p; p += (bytes + 255) & ~(size_t)255; return r;
  };
  float* tp    = (float*)alloc((size_t)6 * 4096 * 4);
  bf16* wq_b   = (bf16*)alloc((size_t)1024 * 1024 * 2);   // wq..wout contiguous for prep
  bf16* wk_b   = (bf16*)alloc((size_t)1024 * 1024 * 2);
  bf16* wv_b   = (bf16*)alloc((size_t)1024 * 1024 * 2);
  bf16* wo_b   = (bf16*)alloc((size_t)1024 * 1024 * 2);
  bf16* wgh_b  = (bf16*)alloc((size_t)8192 * 1024 * 2);   // gate/hidden row-interleaved
  bf16* wout_b = (bf16*)alloc((size_t)1024 * 4096 * 2);
  bf16* xn_b   = (bf16*)alloc((size_t)8192 * 1024 * 2);
  bf16* q_b    = (bf16*)alloc((size_t)8192 * 1024 * 2);
  bf16* k_b    = (bf16*)alloc((size_t)8192 * 1024 * 2);
  bf16* vt_b   = (bf16*)alloc((size_t)8192 * 1024 * 2);
  bf16* ao_b   = (bf16*)alloc((size_t)8192 * 1024 * 2);
  bf16* xmid_b = (bf16*)alloc((size_t)8192 * 1024 * 2);   // residual stream in bf16
  bf16* gh_b   = (bf16*)alloc((size_t)8192 * 4096 * 2);

  // fused weight-convert + t-projections (independent work, one launch)
  prep_kernel<<<8288, 256, 0, stream>>>(wq, wk, wv, wo, gw, hw, ow, wq_b,
      t, agw, abw, aaw, fgw, fbw, faw, tp);
  ada_rms_kernel<0><<<8192, 256, 0, stream>>>(x, tp + 0 * 4096, tp + 1 * 4096, xn_b);
  // fused QKV: m97 structure, N=3072, Q pre-scaled
  gemm_bt_kernel<EPI_QKV3><<<1536, 256, 0, stream>>>(xn_b, wq_b, 3072, 1024,
      nullptr, nullptr, q_b, k_b, vt_b);
  attn_kernel<<<512, 512, 0, stream>>>(q_b, k_b, vt_b, ao_b);
  // O-proj + residual -> xmid (bf16)
  gemm_bt_kernel<EPI_RESID><<<512, 256, 0, stream>>>(ao_b, wo_b, 1024, 1024,
      x, tp + 2 * 4096, xmid_b, nullptr, nullptr);
  ada_rms_kernel<1><<<8192, 256, 0, stream>>>(xmid_b, tp + 3 * 4096, tp + 4 * 4096, xn_b);
  // fused SwiGLU: BN=256 8-phase (best measured for K=1024)
  gemm8p_kernel<EPI8_GH, 256><<<1024, 512, 0, stream>>>(xn_b, wgh_b, 8192, 1024, gh_b, nullptr, nullptr, nullptr, nullptr);
  // final: K=4096, BN=128 8-phase (NITER=32), fused bias+alpha+residual (xmid bf16 via o1)
  gemm8p_kernel<EPI8_FIN, 128><<<256, 512, 0, stream>>>(gh_b, wout_b, 1024, 4096,
      xmid_b, out, nullptr, tp + 5 * 4096, ob);
}

// Round 19
// 513.076 us; speedup vs baseline: 1.0196x; 1.0196x over previous
//
#include <hip/hip_runtime.h>
#include <hip/hip_bf16.h>

typedef __attribute__((ext_vector_type(8))) short short8;
typedef __attribute__((ext_vector_type(4))) short short4v;
typedef __attribute__((ext_vector_type(4))) float f32x4;
using bf16 = __hip_bfloat16;
using lds_bf16 = __attribute__((address_space(3))) bf16;

#define BARF()  asm volatile("s_barrier" ::: "memory")
#define LGKM0() asm volatile("s_waitcnt lgkmcnt(0)" ::: "memory")
#define VMC4()  asm volatile("s_waitcnt vmcnt(4)" ::: "memory")
#define VMC2()  asm volatile("s_waitcnt vmcnt(2)" ::: "memory")
#define VMC0()  asm volatile("s_waitcnt vmcnt(0)" ::: "memory")
#define SCHED0() __builtin_amdgcn_sched_barrier(0)
#define PRIO1() __builtin_amdgcn_s_setprio(1)
#define PRIO0() __builtin_amdgcn_s_setprio(0)

static __device__ __forceinline__ short bfb(float f) {
  bf16 h = __float2bfloat16(f);
  short r; __builtin_memcpy(&r, &h, 2); return r;
}
static __device__ __forceinline__ float b2f(short s) {
  bf16 h; __builtin_memcpy(&h, &s, 2); return __bfloat162float(h);
}

static __device__ __forceinline__ void gld_lds16(const bf16* g, bf16* l) {
  __builtin_amdgcn_global_load_lds(
      (const __attribute__((address_space(1))) void*)g,
      (__attribute__((address_space(3))) void*)l, 16, 0, 0);
}

// opaque LDS read: no compiler-inserted vmcnt vs global_load_lds DMA
static __device__ __forceinline__ short8 dsr(const lds_bf16* b, int imm) {
  short8 v;
  asm volatile("ds_read_b128 %0, %1 offset:%2" : "=v"(v) : "v"(b), "i"(imm));
  return v;
}

// ---------------- fused fp32 -> bf16 weight convert; gate/hidden row-interleaved ----------------
__global__ __launch_bounds__(256) void cvt_all_kernel(
    const float* __restrict__ s0, const float* __restrict__ s1, const float* __restrict__ s2,
    const float* __restrict__ s3, const float* __restrict__ gw, const float* __restrict__ hw,
    const float* __restrict__ ow, bf16* __restrict__ dbase) {
  size_t c = (size_t)blockIdx.x * 256 + threadIdx.x;   // chunk of 8 elements
  const float* src; size_t se;
  if (c < 524288) {
    int seg = (int)(c >> 17);
    src = (seg == 0) ? s0 : (seg == 1) ? s1 : (seg == 2) ? s2 : s3;
    se = (c - ((size_t)seg << 17)) * 8;
  } else if (c < 1572864) {
    size_t lc = c - 524288;
    size_t row = lc >> 7;                  // 0..8191 interleaved rows
    src = (row & 1) ? hw : gw;
    se = ((row >> 1) << 10) + ((lc & 127) << 3);
  } else { src = ow; se = (c - 1572864) * 8; }
  float4 v0 = *(const float4*)(src + se);
  float4 v1 = *(const float4*)(src + se + 4);
  short8 o;
  o[0] = bfb(v0.x); o[1] = bfb(v0.y); o[2] = bfb(v0.z); o[3] = bfb(v0.w);
  o[4] = bfb(v1.x); o[5] = bfb(v1.y); o[6] = bfb(v1.z); o[7] = bfb(v1.w);
  *(short8*)(dbase + c * 8) = o;
}

// ---------------- t projections ----------------
__global__ __launch_bounds__(256) void tproj_kernel(const float* __restrict__ t,
    const float* __restrict__ w0, const float* __restrict__ w1, const float* __restrict__ w2,
    const float* __restrict__ w3, const float* __restrict__ w4, const float* __restrict__ w5,
    float* __restrict__ out) {
  int gid = blockIdx.x * 256 + threadIdx.x;       // 6*4*1024 = 24576
  int s = gid >> 12, rem = gid & 4095;
  int b = rem >> 10, n = rem & 1023;
  const float* w = (s == 0) ? w0 : (s == 1) ? w1 : (s == 2) ? w2 : (s == 3) ? w3 : (s == 4) ? w4 : w5;
  const float4* tv = (const float4*)(t + b * 256);
  const float4* wv = (const float4*)(w + n * 256);
  float acc = 0.f;
  #pragma unroll 8
  for (int j = 0; j < 64; ++j) {
    float4 a = tv[j], c = wv[j];
    acc += a.x * c.x + a.y * c.y + a.z * c.z + a.w * c.w;
  }
  out[gid] = acc;
}

// ---------------- AdaRMSNorm (fp32 or bf16 input) ----------------
template<int BF16IN>
__global__ __launch_bounds__(256) void ada_rms_kernel(const void* __restrict__ xin,
    const float* __restrict__ gamma, const float* __restrict__ beta, bf16* __restrict__ out) {
  int row = blockIdx.x;            // 8192 rows
  int b = row >> 11;
  int tid = threadIdx.x;
  float vx, vy, vz, vw;
  if constexpr (BF16IN) {
    const bf16* xr = (const bf16*)xin + (size_t)row * 1024;
    short4v v = *(const short4v*)(xr + tid * 4);
    vx = b2f(v[0]); vy = b2f(v[1]); vz = b2f(v[2]); vw = b2f(v[3]);
  } else {
    const float* xr = (const float*)xin + (size_t)row * 1024;
    float4 v = *(const float4*)(xr + tid * 4);
    vx = v.x; vy = v.y; vz = v.z; vw = v.w;
  }
  float ss = vx * vx + vy * vy + vz * vz + vw * vw;
  #pragma unroll
  for (int m = 1; m < 64; m <<= 1) ss += __shfl_xor(ss, m);
  __shared__ float red[4];
  if ((tid & 63) == 0) red[tid >> 6] = ss;
  __syncthreads();
  float tot = red[0] + red[1] + red[2] + red[3];
  float rinv = rsqrtf(tot * (1.0f / 1024.0f) + 1e-6f);
  const float* g  = gamma + b * 1024 + tid * 4;
  const float* be = beta  + b * 1024 + tid * 4;
  short4v o;
  o[0] = bfb(g[0] * vx * rinv + be[0]);
  o[1] = bfb(g[1] * vy * rinv + be[1]);
  o[2] = bfb(g[2] * vz * rinv + be[2]);
  o[3] = bfb(g[3] * vw * rinv + be[3]);
  *(short4v*)(out + (size_t)row * 1024 + tid * 4) = o;
}

// ================= 256xBN 8-phase GEMM: asm ds_read + counted vmcnt =================
// BN=256 for GH (K=1024: max MFMA per phase); BN=128 only for FIN (K=4096, NITER=32).
enum { EPI8_GH = 1, EPI8_FIN = 2 };

#define RDA_M(d, mh) { \
  _Pragma("unroll") for (int mq = 0; mq < 4; ++mq) { \
    a[mq][0] = dsr(aB0, (d) * 32768 + ((mh) * 4 + mq) * 2048); \
    a[mq][1] = dsr(aB1, (d) * 32768 + ((mh) * 4 + mq) * 2048); } }
#define RDB0_M(d, nh) { \
  _Pragma("unroll") for (int nq = 0; nq < 2; ++nq) { \
    b0[nq][0] = dsr(bB0, (d) * 32768 + ((nh) * 2 + nq) * 2048); \
    b0[nq][1] = dsr(bB1, (d) * 32768 + ((nh) * 2 + nq) * 2048); } }
#define RDB1_M(d, nh) { \
  _Pragma("unroll") for (int nq = 0; nq < 2; ++nq) { \
    b1[nq][0] = dsr(bB0, (d) * 32768 + ((nh) * 2 + nq) * 2048); \
    b1[nq][1] = dsr(bB1, (d) * 32768 + ((nh) * 2 + nq) * 2048); } }
#define RDB0_F(d) { b0[0][0] = dsr(bB0, (d) * 16384); b0[0][1] = dsr(bB1, (d) * 16384); }
#define RDB1_F(d) { b1[0][0] = dsr(bB0, (d) * 16384 + 2048); b1[0][1] = dsr(bB1, (d) * 16384 + 2048); }

template<int EPI, int BN>
__global__ __launch_bounds__(512, 2) void gemm8p_kernel(
    const bf16* __restrict__ A, const bf16* __restrict__ B,
    int N, int K,
    bf16* __restrict__ o1, float* __restrict__ outF,
    const float* __restrict__ aux1, const float* __restrict__ aux2,
    const float* __restrict__ bias)
{
  constexpr int SB_ELEMS = (BN == 256) ? (2 * 2 * 128 * 64) : (2 * 128 * 64);
  __shared__ __align__(16) bf16 sA[2 * 2 * 128 * 64];  // [dbuf][half][128][64]
  __shared__ __align__(16) bf16 sB[SB_ELEMS];
  const int tid = threadIdx.x;
  const int lane = tid & 63, w = tid >> 6;             // 8 waves: 2M x 4N
  const int wr = w >> 2, wcn = w & 3;
  const int bid = (int)blockIdx.x;
  const int ntn = (BN == 256) ? (N >> 8) : (N >> 7);
  const int trow = (bid / ntn) << 8;
  const int tcol = (bid % ntn) * BN;
  const int fr = lane & 15, hi = lane >> 4;
  const int rbase = hi << 2;
  const int NITER = K >> 7;                            // 2 K-tiles (BK=64) per iter
  const int st_row = (w << 4) + (lane >> 3);           // 0..127 within a half
  const int st_col = (((lane & 7) ^ ((lane >> 3) & 7)) << 3);
  const bf16* AsH0 = A + (size_t)(trow + st_row) * K + st_col;
  const bf16* AsH1 = AsH0 + (size_t)128 * K;
  const bf16* BsH0 = B + (size_t)(tcol + st_row) * K + st_col;
  const bf16* BsH1 = BsH0 + (size_t)128 * K;           // only for BN==256
  const size_t K8 = (size_t)K << 3;
  bf16* dA = sA + (w << 10);
  bf16* dB = sB + (w << 10);

  auto stA = [&](int dbuf, int h, int t) {
    const bf16* s = (h ? AsH1 : AsH0) + (t << 6);
    bf16* d = dA + ((dbuf * 2 + h) << 13);
    gld_lds16(s, d);
    gld_lds16(s + K8, d + 512);
  };
  auto stB2 = [&](int dbuf, int h, int t) {            // BN=256
    const bf16* s = (h ? BsH1 : BsH0) + (t << 6);
    bf16* d = dB + ((dbuf * 2 + h) << 13);
    gld_lds16(s, d);
    gld_lds16(s + K8, d + 512);
  };
  auto stB1 = [&](int dbuf, int t) {                   // BN=128
    const bf16* s = BsH0 + (t << 6);
    bf16* d = dB + (dbuf << 13);
    gld_lds16(s, d);
    gld_lds16(s + K8, d + 512);
  };
  const int colK0 = (hi << 3) ^ ((fr & 7) << 3);
  const int colK1 = (32 + (hi << 3)) ^ ((fr & 7) << 3);
  const lds_bf16* aB0 = (const lds_bf16*)(sA + (wr << 13) + (fr << 6) + colK0);
  const lds_bf16* aB1 = (const lds_bf16*)(sA + (wr << 13) + (fr << 6) + colK1);
  const lds_bf16 *bB0, *bB1;
  if constexpr (BN == 256) {
    bB0 = (const lds_bf16*)(sB + ((wcn >> 1) << 13) + ((wcn & 1) << 12) + (fr << 6) + colK0);
    bB1 = (const lds_bf16*)(sB + ((wcn >> 1) << 13) + ((wcn & 1) << 12) + (fr << 6) + colK1);
  } else {
    bB0 = (const lds_bf16*)(sB + (wcn << 11) + (fr << 6) + colK0);
    bB1 = (const lds_bf16*)(sB + (wcn << 11) + (fr << 6) + colK1);
  }

  f32x4 acc[8][BN / 64] = {};
  short8 a[4][2], b0[2][2], b1[2][2];

  if constexpr (BN == 256) {
    auto QUAD0 = [&](int mh, int nh) {
      #pragma unroll
      for (int kk = 0; kk < 2; ++kk)
        #pragma unroll
        for (int mq = 0; mq < 4; ++mq)
          #pragma unroll
          for (int nq = 0; nq < 2; ++nq)
            acc[mh * 4 + mq][nh * 2 + nq] = __builtin_amdgcn_mfma_f32_16x16x32_bf16(
                a[mq][kk], b0[nq][kk], acc[mh * 4 + mq][nh * 2 + nq], 0, 0, 0);
    };
    auto QUAD1 = [&](int mh, int nh) {
      #pragma unroll
      for (int kk = 0; kk < 2; ++kk)
        #pragma unroll
        for (int mq = 0; mq < 4; ++mq)
          #pragma unroll
          for (int nq = 0; nq < 2; ++nq)
            acc[mh * 4 + mq][nh * 2 + nq] = __builtin_amdgcn_mfma_f32_16x16x32_bf16(
                a[mq][kk], b1[nq][kk], acc[mh * 4 + mq][nh * 2 + nq], 0, 0, 0);
    };
    stB2(0, 0, 0); stB2(0, 1, 0); stA(0, 0, 0); stA(0, 1, 0);
    stB2(1, 0, 1); stB2(1, 1, 1);
    VMC4();
    BARF();
    for (int i = 0; i < NITER; ++i) {
      const int t1 = 2 * i + 1, tn0 = 2 * i + 2, tn1 = 2 * i + 3;
      const bool g = (i != NITER - 1);
      RDA_M(0, 0); RDB0_M(0, 0);
      stA(1, 0, t1);
      BARF(); LGKM0(); SCHED0(); PRIO1(); QUAD0(0, 0); PRIO0(); BARF();
      RDB1_M(0, 1);
      stA(1, 1, t1);
      BARF(); LGKM0(); SCHED0(); PRIO1(); QUAD1(0, 1); PRIO0(); BARF();
      RDA_M(0, 1);
      if (g) stB2(0, 0, tn0);
      BARF(); LGKM0(); SCHED0(); PRIO1(); QUAD1(1, 1); PRIO0(); BARF();
      if (g) stB2(0, 1, tn0);
      BARF(); LGKM0(); SCHED0(); PRIO1(); QUAD0(1, 0); PRIO0();
      if (g) { VMC4(); } else { VMC0(); }
      BARF();
      RDA_M(1, 0); RDB0_M(1, 0);
      if (g) stA(0, 0, tn0);
      BARF(); LGKM0(); SCHED0(); PRIO1(); QUAD0(0, 0); PRIO0(); BARF();
      RDB1_M(1, 1);
      if (g) stA(0, 1, tn0);
      BARF(); LGKM0(); SCHED0(); PRIO1(); QUAD1(0, 1); PRIO0(); BARF();
      RDA_M(1, 1);
      if (g) stB2(1, 0, tn1);
      BARF(); LGKM0(); SCHED0(); PRIO1(); QUAD1(1, 1); PRIO0(); BARF();
      if (g) stB2(1, 1, tn1);
      BARF(); LGKM0(); SCHED0(); PRIO1(); QUAD0(1, 0); PRIO0();
      if (g) { VMC4(); }
      BARF();
    }
  } else {
    auto QUADF0 = [&](int mh) {
      #pragma unroll
      for (int kk = 0; kk < 2; ++kk)
        #pragma unroll
        for (int mq = 0; mq < 4; ++mq)
          acc[mh * 4 + mq][0] = __builtin_amdgcn_mfma_f32_16x16x32_bf16(
              a[mq][kk], b0[0][kk], acc[mh * 4 + mq][0], 0, 0, 0);
    };
    auto QUADF1 = [&](int mh) {
      #pragma unroll
      for (int kk = 0; kk < 2; ++kk)
        #pragma unroll
        for (int mq = 0; mq < 4; ++mq)
          acc[mh * 4 + mq][1] = __builtin_amdgcn_mfma_f32_16x16x32_bf16(
              a[mq][kk], b1[0][kk], acc[mh * 4 + mq][1], 0, 0, 0);
    };
    stB1(0, 0); stA(0, 0, 0); stA(0, 1, 0); stB1(1, 1);
    VMC2();
    BARF();
    for (int i = 0; i < NITER; ++i) {
      const int t1 = 2 * i + 1, tn0 = 2 * i + 2, tn1 = 2 * i + 3;
      const bool g = (i != NITER - 1);
      RDA_M(0, 0); RDB0_F(0);
      stA(1, 0, t1);
      BARF(); LGKM0(); SCHED0(); PRIO1(); QUADF0(0); PRIO0(); BARF();
      RDB1_F(0);
      stA(1, 1, t1);
      BARF(); LGKM0(); SCHED0(); PRIO1(); QUADF1(0); PRIO0(); BARF();
      RDA_M(0, 1);
      if (g) stB1(0, tn0);
      BARF(); LGKM0(); SCHED0(); PRIO1(); QUADF1(1); PRIO0(); BARF();
      BARF(); LGKM0(); SCHED0(); PRIO1(); QUADF0(1); PRIO0();
      if (g) { VMC2(); } else { VMC0(); }
      BARF();
      RDA_M(1, 0); RDB0_F(1);
      if (g) stA(0, 0, tn0);
      BARF(); LGKM0(); SCHED0(); PRIO1(); QUADF0(0); PRIO0(); BARF();
      RDB1_F(1);
      if (g) stA(0, 1, tn0);
      BARF(); LGKM0(); SCHED0(); PRIO1(); QUADF1(0); PRIO0(); BARF();
      RDA_M(1, 1);
      if (g) stB1(1, tn1);
      BARF(); LGKM0(); SCHED0(); PRIO1(); QUADF1(1); PRIO0(); BARF();
      BARF(); LGKM0(); SCHED0(); PRIO1(); QUADF0(1); PRIO0();
      if (g) { VMC2(); }
      BARF();
    }
  }

  // epilogue
  #pragma unroll
  for (int m = 0; m < 8; ++m)
  #pragma unroll
  for (int n = 0; n < BN / 64; ++n)
  #pragma unroll
  for (int r = 0; r < 4; ++r) {
    int row = trow + (wr << 7) + m * 16 + rbase + r;
    int col = tcol + wcn * (BN / 4) + n * 16 + fr;
    float c = acc[m][n][r];
    if constexpr (EPI == EPI8_GH) {
      float other = __shfl_xor(c, 1);
      if (!(fr & 1)) {
        float sg = c / (1.f + __expf(-c));
        o1[(size_t)row * 4096 + (col >> 1)] = __float2bfloat16(sg * other);
      }
    } else {  // EPI8_FIN: out = xmid_b(bf16) + aux2*(c + bias)
      int b = row >> 11;
      size_t idx = (size_t)row * 1024 + col;
      outF[idx] = __bfloat162float(o1[idx]) + aux2[b * 1024 + col] * (c + bias[col]);
    }
  }
}

// ---------------- m97-structure GEMM: O-proj (bf16 xmid out), fused QKV ----------------
enum { EPI_RESID = 0, EPI_QKV3 = 2 };

template<int EPI>
__global__ __launch_bounds__(256) void gemm_bt_kernel(
    const bf16* __restrict__ A, const bf16* __restrict__ B,
    int N, int K,
    const float* __restrict__ aux1, const float* __restrict__ aux2,
    bf16* __restrict__ oq, bf16* __restrict__ okk, bf16* __restrict__ ovt)
{
  __shared__ __align__(16) bf16 As[128][32];
  __shared__ __align__(16) bf16 Bs[128][32];
  const int tid = threadIdx.x;
  const int lane = tid & 63, wid = tid >> 6;
  const int wr = wid >> 1, wc = wid & 1;
  const int bid = (int)blockIdx.x;
  const int ntn = N >> 7;
  const int trow = (bid / ntn) << 7;
  const int tcol = (bid % ntn) << 7;
  const int fr = lane & 15, fc = (lane >> 4) << 3;
  const int rbase = (lane >> 4) << 2;
  const bf16* gA0 = A + (size_t)(trow + wid * 32 + (lane >> 2)) * K + ((lane & 3) << 3);
  const bf16* gA1 = gA0 + (size_t)16 * K;
  const bf16* gB0 = B + (size_t)(tcol + wid * 32 + (lane >> 2)) * K + ((lane & 3) << 3);
  const bf16* gB1 = gB0 + (size_t)16 * K;
  bf16* lA0 = &As[wid * 32][0];
  bf16* lA1 = &As[wid * 32 + 16][0];
  bf16* lB0 = &Bs[wid * 32][0];
  bf16* lB1 = &Bs[wid * 32 + 16][0];
  f32x4 acc[4][4] = {};
  for (int k0 = 0; k0 < K; k0 += 32) {
    __syncthreads();
    gld_lds16(gA0 + k0, lA0);
    gld_lds16(gA1 + k0, lA1);
    gld_lds16(gB0 + k0, lB0);
    gld_lds16(gB1 + k0, lB1);
    __syncthreads();
    short8 af[4], bfr[4];
    #pragma unroll
    for (int m = 0; m < 4; ++m) af[m] = *(const short8*)&As[wr * 64 + m * 16 + fr][fc];
    #pragma unroll
    for (int n = 0; n < 4; ++n) bfr[n] = *(const short8*)&Bs[wc * 64 + n * 16 + fr][fc];
    #pragma unroll
    for (int m = 0; m < 4; ++m)
      #pragma unroll
      for (int n = 0; n < 4; ++n)
        acc[m][n] = __builtin_amdgcn_mfma_f32_16x16x32_bf16(af[m], bfr[n], acc[m][n], 0, 0, 0);
  }
  if constexpr (EPI == EPI_QKV3) {
    #pragma unroll
    for (int m = 0; m < 4; ++m)
    #pragma unroll
    for (int n = 0; n < 4; ++n) {
      int row0 = trow + wr * 64 + m * 16 + rbase;
      int col  = tcol + wc * 64 + n * 16 + fr;
      int seg = col >> 10, cc = col & 1023;
      int bb = row0 >> 11, h2 = cc >> 6, dd = cc & 63;
      if (seg == 0) {
        #pragma unroll
        for (int r = 0; r < 4; ++r) {
          int l = (row0 + r) & 2047;
          oq[(((size_t)(bb * 16 + h2) * 2048 + l) << 6) + dd] =
              __float2bfloat16(acc[m][n][r] * 0.18033688f);
        }
      } else if (seg == 1) {
        #pragma unroll
        for (int r = 0; r < 4; ++r) {
          int l = (row0 + r) & 2047;
          okk[(((size_t)(bb * 16 + h2) * 2048 + l) << 6) + dd] = __float2bfloat16(acc[m][n][r]);
        }
      } else {   // V^T: one b64 store
        int l = row0 & 2047;
        short4v o4;
        #pragma unroll
        for (int r = 0; r < 4; ++r) o4[r] = bfb(acc[m][n][r]);
        *(short4v*)&ovt[(((size_t)(bb * 16 + h2) * 64 + dd) << 11) + l] = o4;
      }
    }
  } else {  // EPI_RESID: xmid_b = bf16(x + alpha*c)
    #pragma unroll
    for (int m = 0; m < 4; ++m)
    #pragma unroll
    for (int n = 0; n < 4; ++n)
    #pragma unroll
    for (int r = 0; r < 4; ++r) {
      int row = trow + wr * 64 + m * 16 + rbase + r;
      int col = tcol + wc * 64 + n * 16 + fr;
      int b = row >> 11;
      size_t idx = (size_t)row * 1024 + col;
      oq[idx] = __float2bfloat16(aux1[idx] + aux2[b * 1024 + col] * acc[m][n][r]);
    }
  }
}

// ---------------- flash attention QBLK=256, 8 waves; dbuf LDS K/V, QK first ----------------
__global__ __launch_bounds__(512, 4) void attn_kernel(const bf16* __restrict__ q,
    const bf16* __restrict__ k, const bf16* __restrict__ vt, bf16* __restrict__ o) {
  const int id = blockIdx.x;
  const int bh = id & 63;
  const int qt = id >> 6;          // 0..7, 256 q-rows each
  const int b = bh >> 4, h = bh & 15;
  __shared__ __align__(16) bf16 Ks[2][64][72];   // [dbuf][kk][d]
  __shared__ __align__(16) bf16 Vs[2][64][72];   // [dbuf][d][kk]
  __shared__ __align__(16) bf16 Ps[256][72];     // [q_local][kk] (same-wave rows only)
  const int tid = threadIdx.x, lane = tid & 63, w = tid >> 6;   // 8 waves, 32 q-rows each
  const int fr = lane & 15, hi = lane >> 4;
  const int fc = hi << 3, rbase = hi << 2;
  const bf16* qbase = q + ((size_t)bh * 2048 + qt * 256) * 64;
  const bf16* kbase = k + (size_t)bh * 2048 * 64;
  const bf16* vbase = vt + (size_t)bh * 64 * 2048;
  short8 qf[2][2];
  #pragma unroll
  for (int nq = 0; nq < 2; ++nq)
    #pragma unroll
    for (int ks = 0; ks < 2; ++ks)
      qf[nq][ks] = *(const short8*)(qbase + (size_t)(w * 32 + nq * 16 + fr) * 64 + ks * 32 + fc);
  short8 onesf;
  #pragma unroll
  for (int j = 0; j < 8; ++j) onesf[j] = (short)0x3F80;   // bf16 1.0
  f32x4 accO[4][2] = {};
  f32x4 accD[2] = {};
  const int sr = tid >> 3, sc = (tid & 7) << 3;   // 512 threads: rows 0..63 x 8 col-chunks
  *(short8*)&Ks[0][sr][sc] = *(const short8*)(kbase + (size_t)sr * 64 + sc);
  *(short8*)&Vs[0][sr][sc] = *(const short8*)(vbase + (size_t)sr * 2048 + sc);
  short8 rk = *(const short8*)(kbase + (size_t)(64 + sr) * 64 + sc);
  short8 rv = *(const short8*)(vbase + (size_t)sr * 2048 + 64 + sc);
  __syncthreads();
  for (int kt = 0; kt < 2048; kt += 64) {
    const int cur = (kt >> 6) & 1;
    // QK^T first (reads current buffers immediately at tile top)
    f32x4 s[4][2] = {};
    #pragma unroll
    for (int ks = 0; ks < 2; ++ks) {
      short8 kf[4];
      #pragma unroll
      for (int mk = 0; mk < 4; ++mk) kf[mk] = *(const short8*)&Ks[cur][mk * 16 + fr][ks * 32 + fc];
      #pragma unroll
      for (int mk = 0; mk < 4; ++mk)
        #pragma unroll
        for (int nq = 0; nq < 2; ++nq)
          s[mk][nq] = __builtin_amdgcn_mfma_f32_16x16x32_bf16(kf[mk], qf[nq][ks], s[mk][nq], 0, 0, 0);
    }
    // stage tile t+1 into inactive buffer; issue t+2 loads (overlap with exp/P phase)
    if (kt + 64 < 2048) {
      *(short8*)&Ks[cur ^ 1][sr][sc] = rk;
      *(short8*)&Vs[cur ^ 1][sr][sc] = rv;
      if (kt + 128 < 2048) {
        rk = *(const short8*)(kbase + (size_t)(kt + 128 + sr) * 64 + sc);
        rv = *(const short8*)(vbase + (size_t)sr * 2048 + kt + 128 + sc);
      }
    }
    #pragma unroll
    for (int mk = 0; mk < 4; ++mk)
      #pragma unroll
      for (int nq = 0; nq < 2; ++nq) {
        short4v pk;
        pk[0] = bfb(exp2f(s[mk][nq][0]));
        pk[1] = bfb(exp2f(s[mk][nq][1]));
        pk[2] = bfb(exp2f(s[mk][nq][2]));
        pk[3] = bfb(exp2f(s[mk][nq][3]));
        *(short4v*)&Ps[w * 32 + nq * 16 + fr][mk * 16 + rbase] = pk;
      }
    #pragma unroll
    for (int ks2 = 0; ks2 < 2; ++ks2) {
      short8 av[4], bp[2];
      #pragma unroll
      for (int nd = 0; nd < 4; ++nd) av[nd] = *(const short8*)&Vs[cur][nd * 16 + fr][ks2 * 32 + fc];
      #pragma unroll
      for (int nq = 0; nq < 2; ++nq) bp[nq] = *(const short8*)&Ps[w * 32 + nq * 16 + fr][ks2 * 32 + fc];
      #pragma unroll
      for (int nd = 0; nd < 4; ++nd)
        #pragma unroll
        for (int nq = 0; nq < 2; ++nq)
          accO[nd][nq] = __builtin_amdgcn_mfma_f32_16x16x32_bf16(av[nd], bp[nq], accO[nd][nq], 0, 0, 0);
      #pragma unroll
      for (int nq = 0; nq < 2; ++nq)
        accD[nq] = __builtin_amdgcn_mfma_f32_16x16x32_bf16(onesf, bp[nq], accD[nq], 0, 0, 0);
    }
    __syncthreads();   // single barrier per tile
  }
  float rd[2];
  #pragma unroll
  for (int nq = 0; nq < 2; ++nq) rd[nq] = 1.0f / accD[nq][0];
  #pragma unroll
  for (int nd = 0; nd < 4; ++nd)
    #pragma unroll
    for (int nq = 0; nq < 2; ++nq) {
      short4v ov;
      #pragma unroll
      for (int r = 0; r < 4; ++r) ov[r] = bfb(accO[nd][nq][r] * rd[nq]);
      int qrow = qt * 256 + w * 32 + nq * 16 + fr;
      int col = h * 64 + nd * 16 + rbase;
      *(short4v*)&o[((size_t)b * 2048 + qrow) * 1024 + col] = ov;
    }
}

extern "C" void kernel_launch(void* const* d_in, const int* in_sizes, int n_in,
                              void* d_out, int out_size, void* d_ws, size_t ws_size,
                              hipStream_t stream) {
  (void)in_sizes; (void)n_in; (void)out_size; (void)ws_size;
  const float* x   = (const float*)d_in[0];
  const float* t   = (const float*)d_in[1];
  const float* agw = (const float*)d_in[2];
  const float* abw = (const float*)d_in[3];
  const float* wq  = (const float*)d_in[4];
  const float* wk  = (const float*)d_in[5];
  const float* wv  = (const float*)d_in[6];
  const float* wo  = (const float*)d_in[7];
  const float* aaw = (const float*)d_in[8];
  const float* fgw = (const float*)d_in[9];
  const float* fbw = (const float*)d_in[10];
  const float* gw  = (const float*)d_in[11];
  const float* hw  = (const float*)d_in[12];
  const float* ow  = (const float*)d_in[13];
  const float* ob  = (const float*)d_in[14];
  const float* faw = (const float*)d_in[15];
  float* out = (float*)d_out;

  char* p = (char*)d_ws;
  auto alloc = [&](size_t bytes) -> char* {
    char* r = p; p += (bytes + 255) & ~(size_t)255; return r;
  };
  float* tp    = (float*)alloc((size_t)6 * 4096 * 4);
  bf16* wq_b   = (bf16*)alloc((size_t)1024 * 1024 * 2);   // wq..wout contiguous for cvt_all
  bf16* wk_b   = (bf16*)alloc((size_t)1024 * 1024 * 2);
  bf16* wv_b   = (bf16*)alloc((size_t)1024 * 1024 * 2);
  bf16* wo_b   = (bf16*)alloc((size_t)1024 * 1024 * 2);
  bf16* wgh_b  = (bf16*)alloc((size_t)8192 * 1024 * 2);   // gate/hidden row-interleaved
  bf16* wout_b = (bf16*)alloc((size_t)1024 * 4096 * 2);
  bf16* xn_b   = (bf16*)alloc((size_t)8192 * 1024 * 2);
  bf16* q_b    = (bf16*)alloc((size_t)8192 * 1024 * 2);
  bf16* k_b    = (bf16*)alloc((size_t)8192 * 1024 * 2);
  bf16* vt_b   = (bf16*)alloc((size_t)8192 * 1024 * 2);
  bf16* ao_b   = (bf16*)alloc((size_t)8192 * 1024 * 2);
  bf16* xmid_b = (bf16*)alloc((size_t)8192 * 1024 * 2);   // residual stream in bf16
  bf16* gh_b   = (bf16*)alloc((size_t)8192 * 4096 * 2);

  cvt_all_kernel<<<8192, 256, 0, stream>>>(wq, wk, wv, wo, gw, hw, ow, wq_b);
  tproj_kernel<<<96, 256, 0, stream>>>(t, agw, abw, aaw, fgw, fbw, faw, tp);
  ada_rms_kernel<0><<<8192, 256, 0, stream>>>(x, tp + 0 * 4096, tp + 1 * 4096, xn_b);
  // fused QKV: m97 structure, N=3072, Q pre-scaled
  gemm_bt_kernel<EPI_QKV3><<<1536, 256, 0, stream>>>(xn_b, wq_b, 3072, 1024,
      nullptr, nullptr, q_b, k_b, vt_b);
  attn_kernel<<<512, 512, 0, stream>>>(q_b, k_b, vt_b, ao_b);
  // O-proj + residual -> xmid (bf16)
  gemm_bt_kernel<EPI_RESID><<<512, 256, 0, stream>>>(ao_b, wo_b, 1024, 1024,
      x, tp + 2 * 4096, xmid_b, nullptr, nullptr);
  ada_rms_kernel<1><<<8192, 256, 0, stream>>>(xmid_b, tp + 3 * 4096, tp + 4 * 4096, xn_b);
  // fused SwiGLU: BN=256 8-phase (best measured for K=1024)
  gemm8p_kernel<EPI8_GH, 256><<<1024, 512, 0, stream>>>(xn_b, wgh_b, 8192, 1024, gh_b, nullptr, nullptr, nullptr, nullptr);
  // final: K=4096, BN=128 8-phase (NITER=32), fused bias+alpha+residual (xmid bf16 via o1)
  gemm8p_kernel<EPI8_FIN, 128><<<256, 512, 0, stream>>>(gh_b, wout_b, 1024, 4096,
      xmid_b, out, nullptr, tp + 5 * 4096, ob);
}